// Round 12
// baseline (231.075 us; speedup 1.0000x reference)
//
#include <hip/hip_runtime.h>

constexpr int S    = 256;
constexpr int D    = 32;
constexpr int NH   = 4;
constexpr int DH   = 8;
constexpr int DFF  = 64;
constexpr int NL   = 4;
constexpr int IND  = 58;
constexpr int HOUT = 25;
constexpr int TPB  = 256;  // 1 window/block, 4 waves; 2 blocks/CU (proven shell)
                           // 512-thread variants SPILL (round 3). Occupancy is
                           // GRID-capped (512 blk): do not chase occupancy.

typedef float  f2 __attribute__((ext_vector_type(2)));
typedef float  f4 __attribute__((ext_vector_type(4)));
typedef __fp16 h2 __attribute__((ext_vector_type(2)));
typedef __fp16 h4 __attribute__((ext_vector_type(4)));
typedef __fp16 h8 __attribute__((ext_vector_type(8)));

__device__ __forceinline__ f4 MFMA16(h4 a, h4 b, f4 c) {
  return __builtin_amdgcn_mfma_f32_16x16x16f16(a, b, c, 0, 0, 0);
}
// CDNA4-native K=32 shape. A/B frags = cat(K-half0, K-half1) on BOTH
// operands -> internal k-slot mapping cancels (layout-safe, r6-verified).
__device__ __forceinline__ f4 MFMA32(h8 a, h8 b, f4 c) {
  return __builtin_amdgcn_mfma_f32_16x16x32_f16(a, b, c, 0, 0, 0);
}
__device__ __forceinline__ h8 hcat(h4 a, h4 b) {
  return __builtin_shufflevector(a, b, 0, 1, 2, 3, 4, 5, 6, 7);
}

// LDS map (bytes), 32 KB. Liveness per layer:
//  HOFF: h f16 (ph1 src, all rows) -> h' f16 (G34 src, own rows)
//  VOFF: attn O (ph2 out, all rows) -> O'/O'' f16 (G2/G34 out, own rows)
constexpr int HOFF  = 0;      // 16 KB  [256][32] f16, 8B chunks ^rkey(tok)
constexpr int VOFF  = 16384;  // 16 KB  [256][32] f16, same swizzle
constexpr int LDSSZ = 32768;

// r12 swizzle key: (tok^(tok>>3))&7. The old key (tok&7) left the 8 lanes
// with equal tok mod 8 (rows 8 apart, same parity -> same bank set) on ONE
// bank pair in the per-thread row paths (store_h16/add_row32/O-store):
// an 8-way conflict (~2.94x, m136). Folding tok>>3 gives those 8 lanes 8
// distinct keys -> conflict-free; tile reads stay <=2-way (free).
__device__ __forceinline__ int rkey(int tok) { return (tok ^ (tok >> 3)) & 7; }

__device__ __forceinline__ unsigned pk2(float a, float b) {
  h2 h = __builtin_amdgcn_cvt_pkrtz(a, b);
  return __builtin_bit_cast(unsigned, h);
}

__device__ __forceinline__ float exp2fast(float x) {
#if __has_builtin(__builtin_amdgcn_exp2f)
  return __builtin_amdgcn_exp2f(x);   // v_exp_f32 = 2^x, one trans op
#else
  return exp2f(x);
#endif
}

// Compiler fence for same-wave LDS RAW (r9: wave_barrier only).
__device__ __forceinline__ void wave_fence() {
  __builtin_amdgcn_wave_barrier();
}

// packed-fp32 dot. All register-array loops must FULLY unroll (r3 lesson).
template<int NF2>
__device__ __forceinline__ float dotp(const float* __restrict__ w,
                                      const float* __restrict__ v) {
  const f2* W = (const f2*)w;
  const f2* V = (const f2*)v;
  f2 a0 = {0.f, 0.f}, a1 = {0.f, 0.f};
#pragma unroll
  for (int i = 0; i < NF2; i += 2) a0 += V[i] * W[i];
#pragma unroll
  for (int i = 1; i < NF2; i += 2) a1 += V[i] * W[i];
  f2 s = a0 + a1;
  return s.x + s.y;
}

// tanh-approx GELU via exp2 (log2e folded; verified family r7-r10)
__device__ __forceinline__ float gelu(float x) {
  float u = 2.3022082f * fmaf(0.044715f * x * x, x, x);  // 1.59576912*log2(e)
  return x * __builtin_amdgcn_rcpf(1.0f + exp2fast(-u));
}

// LayerNorm on 32 f32 regs, packed-f32 (v_pk_*) form.
__device__ __forceinline__ void lnorm(float* h, const float* __restrict__ g,
                                      const float* __restrict__ b) {
  f2* hv = (f2*)h;
  f2 s0 = hv[0], s1 = hv[1];
#pragma unroll
  for (int i = 2; i < 16; i += 2) { s0 += hv[i]; s1 += hv[i + 1]; }
  f2 s = s0 + s1;
  const float m = (s.x + s.y) * (1.0f / D);
  const f2 m2 = {m, m};
  f2 v0 = {0.f, 0.f}, v1 = {0.f, 0.f};
#pragma unroll
  for (int i = 0; i < 16; i += 2) {
    f2 c0 = hv[i] - m2;     v0 += c0 * c0;
    f2 c1 = hv[i + 1] - m2; v1 += c1 * c1;
  }
  f2 vs = v0 + v1;
  const float inv = __builtin_amdgcn_rsqf((vs.x + vs.y) * (1.0f / D) + 1e-5f);
  const f2 inv2 = {inv, inv};
  const f2 mi2 = {-m * inv, -m * inv};
  const f2* g2 = (const f2*)g;
  const f2* b2 = (const f2*)b;
#pragma unroll
  for (int i = 0; i < 16; ++i) {
    f2 t = hv[i] * inv2 + mi2;   // (h-m)*inv  as pk_fma
    hv[i] = t * g2[i] + b2[i];   // *g + b     as pk_fma
  }
}

__device__ __forceinline__ void embed_token(
    const float* __restrict__ xrow, int lay,
    const float* __restrict__ fpw, const float* __restrict__ fpb,
    const float* __restrict__ lemb, const float* __restrict__ fB,
    float* __restrict__ h) {
  float xr[IND];
  const f2* xv = (const f2*)xrow;
#pragma unroll
  for (int i = 0; i < 29; ++i) { f2 t = xv[i]; xr[2 * i] = t.x; xr[2 * i + 1] = t.y; }
  const float* le = lemb + lay * D;
  float pe[D];
#pragma unroll
  for (int k = 0; k < 16; ++k) {
    // sin(2*pi*t) = v_sin(fract(t)) in revolutions (verified r9/r10)
    float t = xr[0] * fB[k] + xr[1] * fB[16 + k] + xr[2] * fB[32 + k];
#if __has_builtin(__builtin_amdgcn_sinf) && __has_builtin(__builtin_amdgcn_cosf) && __has_builtin(__builtin_amdgcn_fractf)
    float u = __builtin_amdgcn_fractf(t);
    pe[k]      = __builtin_amdgcn_sinf(u);
    pe[16 + k] = __builtin_amdgcn_cosf(u);
#else
    float sv, cv;
    sincosf(6.2831853071795864f * (t - floorf(t)), &sv, &cv);
    pe[k] = sv; pe[16 + k] = cv;
#endif
  }
#pragma unroll
  for (int d = 0; d < D; ++d)
    h[d] = dotp<29>(fpw + d * IND, xr) + fpb[d] + le[d] + pe[d];
}

// ---- shared fragment helpers (layouts verified r8/r11; key r12) ----
__device__ __forceinline__ h4 bfrag(const float* __restrict__ W, int row,
                                    int K, int kh, int quad) {
  f4 w = *(const f4*)(W + row * K + kh * 16 + quad * 4);
  uint2 p{pk2(w.x, w.y), pk2(w.z, w.w)};
  return __builtin_bit_cast(h4, p);
}
__device__ __forceinline__ h8 bfrag8(const float* __restrict__ W, int row,
                                     int quad) {
  return hcat(bfrag(W, row, 32, 0, quad), bfrag(W, row, 32, 1, quad));
}
// K=32 weight row with scale folded (for QKV weight frags)
__device__ __forceinline__ h8 wfrag8(const float* __restrict__ W, int row,
                                     int quad, float sc) {
  f4 w0 = *(const f4*)(W + row * D + quad * 4) * sc;
  f4 w1 = *(const f4*)(W + row * D + 16 + quad * 4) * sc;
  uint2 p0{pk2(w0.x, w0.y), pk2(w0.z, w0.w)};
  uint2 p1{pk2(w1.x, w1.y), pk2(w1.z, w1.w)};
  return hcat(__builtin_bit_cast(h4, p0), __builtin_bit_cast(h4, p1));
}
// token frag from [tok][32] f16, 8B chunks swizzled ^rkey(tok)
__device__ __forceinline__ h4 afrag32(const unsigned char* sm, int base,
                                      int tok, int kh, int quad) {
  return *(const h4*)(sm + base + tok * 64 + (((kh * 4 + quad) ^ rkey(tok)) * 8));
}
__device__ __forceinline__ h8 afrag8(const unsigned char* sm, int base,
                                     int tok, int quad) {
  return hcat(afrag32(sm, base, tok, 0, quad), afrag32(sm, base, tok, 1, quad));
}

// Write this thread's h (f32 regs) as swizzled f16 row into HOFF.
__device__ __forceinline__ void store_h16(unsigned char* sm, int tok,
                                          const float* __restrict__ h) {
  const int k = rkey(tok);
#pragma unroll
  for (int c = 0; c < 8; ++c) {
    uint2 p{pk2(h[4 * c], h[4 * c + 1]), pk2(h[4 * c + 2], h[4 * c + 3])};
    *(uint2*)(sm + HOFF + tok * 64 + ((c ^ k) * 8)) = p;
  }
}
// Read a swizzled [tok][32] f16 row, accumulate into h (residual add).
__device__ __forceinline__ void add_row32(const unsigned char* sm, int base,
                                          int tok, float* __restrict__ h) {
  f2* hv = (f2*)h;
  const int k = rkey(tok);
#pragma unroll
  for (int c = 0; c < 8; ++c) {
    h4 q = *(const h4*)(sm + base + tok * 64 + ((c ^ k) * 8));
    f2 lo = {(float)q[0], (float)q[1]};
    f2 hi = {(float)q[2], (float)q[3]};
    hv[2 * c] += lo;
    hv[2 * c + 1] += hi;
  }
}

// launch_bounds: ONLY (256,2) is spill-free for this family (r5-r10, round 3).
__global__ void __launch_bounds__(TPB, 2)
spai_fused(const float* __restrict__ x,    const int*   __restrict__ layers,
           const float* __restrict__ fpw,  const float* __restrict__ fpb,
           const float* __restrict__ lemb, const float* __restrict__ fB,
           const float* __restrict__ ipw,  const float* __restrict__ ipb,
           const float* __restrict__ opw,  const float* __restrict__ opb,
           const float* __restrict__ ln1g, const float* __restrict__ ln1b,
           const float* __restrict__ w1,   const float* __restrict__ b1,
           const float* __restrict__ w2,   const float* __restrict__ b2,
           const float* __restrict__ ln2g, const float* __restrict__ ln2b,
           const float* __restrict__ nog,  const float* __restrict__ nob,
           const float* __restrict__ hw,   const float* __restrict__ hb,
           float* __restrict__ out) {
  __shared__ __align__(16) unsigned char sm[LDSSZ];
  const int tid    = threadIdx.x;
  const int lane   = tid & 63;
  const int wave   = tid >> 6;   // 0..3 == head index
  const int n16    = lane & 15;
  const int quad   = lane >> 4;
  const int pairi  = wave >> 1;  // head pair {0,1} / {2,3}
  const int parity = wave & 1;   // head = 2*pairi + parity
  const size_t blk_tok = (size_t)blockIdx.x * S;

  float h[D];
  embed_token(x + (blk_tok + tid) * IND, layers[blk_tok + tid],
              fpw, fpb, lemb, fB, h);
  store_h16(sm, tid, h);   // published by barrier A (l=0)

  for (int l = 0; l < NL; ++l) {
    // Barrier A: h stores (own rows) -> ph1 h reads (all rows); also
    // separates prev-layer VOFF readers from this layer's ph2 O writes.
    __syncthreads();

    const float* Wi = ipw + l * (3 * D) * D;
    const float* Bi = ipb + l * (3 * D);

    // ---- ph1: per-wave head-pair QKV over ALL 16 token tiles -------------
    // Pair waves duplicate this. C-frags ARE ph2's operand frags; handoff is
    // SAME-THREAD -> Q/K/V all live in registers (r10). Odd head's V via
    // weight-row XOR 8 (bit-identical to shfl). Q pre-scaled by
    // (1/sqrt(dh))*log2e; other head's Q half zeroed once at creation.
    h4 Kf[16], Vf[16], Qf[16];
    {
      const float scq = 0.51006973f;  // 0.35355339 * log2(e)
      h8 BfQ = wfrag8(Wi, pairi * 16 + n16, quad, scq);
      h8 BfK = wfrag8(Wi + 32 * D, pairi * 16 + n16, quad, 1.0f);
      const int vrow = pairi * 16 + (n16 ^ (parity << 3));
      h8 BfV = wfrag8(Wi + 64 * D, vrow, quad, 1.0f);
      f4 bq = *(const f4*)(Bi + pairi * 16 + quad * 4) * scq;
      f4 bk = *(const f4*)(Bi + 32 + pairi * 16 + quad * 4);
      const float bvv = Bi[64 + vrow];
      const f4 bv4 = {bvv, bvv, bvv, bvv};
      const unsigned fill = (n16 == 8) ? 0x3C003C00u : 0u;  // lsum ones row
      const bool qlive = (quad >> 1) == parity;
#pragma unroll
      for (int it = 0; it < 16; ++it) {
        const int tok = it * 16 + n16;
        h8 Ah = afrag8(sm, HOFF, tok, quad);
        f4 Cq = MFMA32(BfQ, Ah, bq);   // col n16 = token, row quad*4+r = feat
        f4 Ck = MFMA32(BfK, Ah, bk);
        f4 Cv = MFMA32(Ah, BfV, bv4);  // col n16 = feat, C[r] = token quad*4+r
        uint2 q{pk2(Cq[0], Cq[1]), pk2(Cq[2], Cq[3])};
        if (!qlive) { q.x = 0u; q.y = 0u; }  // zero other head's k-half
        Qf[it] = __builtin_bit_cast(h4, q);
        uint2 kk{pk2(Ck[0], Ck[1]), pk2(Ck[2], Ck[3])};
        Kf[it] = __builtin_bit_cast(h4, kk);
        uint2 v{pk2(Cv[0], Cv[1]), pk2(Cv[2], Cv[3])};
        if (n16 >= 8) { v.x = fill; v.y = fill; }  // row 8 ones, 9-15 zero
        Vf[it] = __builtin_bit_cast(h4, v);
      }
    }
    // No fence: ph1->ph2 is pure register dataflow.

    // ---- ph2: flash attention (wave = head), QKV fully in registers ------
    // r11: V8 pairs prebuilt; QK^T software-pipelined (MFMA latency hides
    // under the exp block). r12: pipeline extended ACROSS the it boundary —
    // at j2==7 the NEXT it's first score pair is issued, so the epilogue
    // (rcp -> bpermute(LDS lat) -> mul -> pack -> store) overlaps the next
    // iteration's MFMA chain instead of heading a stall.
    {
      const int hh  = wave;
      const int m   = n16;
      const int obase = hh * 2 + quad;    // O feat-block (valid quad<2)
      const f4 Z = {0.f, 0.f, 0.f, 0.f};
      h8 V8a[8];
#pragma unroll
      for (int j2 = 0; j2 < 8; ++j2) V8a[j2] = hcat(Vf[2 * j2], Vf[2 * j2 + 1]);
      __builtin_amdgcn_s_setprio(1);
      f4 T0 = MFMA16(Kf[0], Qf[0], Z);
      f4 T1 = MFMA16(Kf[1], Qf[0], Z);
#pragma unroll
      for (int it = 0; it < 16; ++it) {
        const int ti = it * 16 + m;
        h4 Q4  = Qf[it];
        h4 Q4n = (it < 15) ? Qf[(it < 15) ? it + 1 : 0] : Qf[0];
        f4 Of0 = Z, Of1 = Z;
#pragma unroll
        for (int j2 = 0; j2 < 8; ++j2) {
          f4 nT0, nT1;
          if (j2 < 7) {            // prefetch this it's next tile pair
            nT0 = MFMA16(Kf[2 * j2 + 2], Q4, Z);
            nT1 = MFMA16(Kf[2 * j2 + 3], Q4, Z);
          } else if (it < 15) {    // prefetch NEXT it's first tile pair
            nT0 = MFMA16(Kf[0], Q4n, Z);
            nT1 = MFMA16(Kf[1], Q4n, Z);
          } else {
            nT0 = Z; nT1 = Z;
          }
          uint2 pa{pk2(exp2fast(T0[0]), exp2fast(T0[1])),
                   pk2(exp2fast(T0[2]), exp2fast(T0[3]))};
          uint2 pb{pk2(exp2fast(T1[0]), exp2fast(T1[1])),
                   pk2(exp2fast(T1[2]), exp2fast(T1[3]))};
          h8 P8 = hcat(__builtin_bit_cast(h4, pa), __builtin_bit_cast(h4, pb));
          if (j2 & 1) Of1 = MFMA32(V8a[j2], P8, Of1);
          else        Of0 = MFMA32(V8a[j2], P8, Of0);
          T0 = nT0; T1 = nT1;
        }
        f4 Of = Of0 + Of1;
        // C row 8 (quad==2, elem 0) = softmax denominator (lsum trick)
        float rinv = __builtin_amdgcn_rcpf(Of[0]);
        rinv = __builtin_bit_cast(
            float, __builtin_amdgcn_ds_bpermute(
                       (32 + m) << 2, __builtin_bit_cast(int, rinv)));
        if (quad < 2) {  // rows 0..7 = O features hh*8+quad*4+r of token ti
          f4 o = Of * rinv;
          uint2 p{pk2(o[0], o[1]), pk2(o[2], o[3])};
          *(uint2*)(sm + VOFF + ti * 64 + ((obase ^ rkey(ti)) * 8)) = p;
        }
      }
      __builtin_amdgcn_s_setprio(0);
    }
    // Barrier B: O (cross-head chunks, VOFF) visible to all; also all ph1
    // h-reads finished -> HOFF rows reusable below.
    __syncthreads();

    // ---- GEMM2: O'^T = Wo x O^T; read VOFF, write VOFF own rows ----------
    // (read-then-write same row by same lane, DS in-order within wave)
    {
      const float* Wo = opw + l * D * D;
      const float* Bo = opb + l * D;
      h8 WoF[2]; f4 bo2[2];
#pragma unroll
      for (int nt = 0; nt < 2; ++nt) {
        bo2[nt] = *(const f4*)(Bo + nt * 16 + quad * 4);
        WoF[nt] = bfrag8(Wo, nt * 16 + n16, quad);
      }
#pragma unroll
      for (int ii = 0; ii < 4; ++ii) {
        const int tok = (wave * 4 + ii) * 16 + n16;
        const int rk = rkey(tok);
        h8 A8 = afrag8(sm, VOFF, tok, quad);
#pragma unroll
        for (int nt = 0; nt < 2; ++nt) {
          f4 C = MFMA32(WoF[nt], A8, bo2[nt]);
          uint2 p{pk2(C[0], C[1]), pk2(C[2], C[3])};
          *(uint2*)(sm + VOFF + tok * 64 + (((nt * 4 + quad) ^ rk) * 8)) = p;
        }
      }
    }
    wave_fence();  // O' rows are own-wave

    // ---- token: h += O'; LN1; h' f16 -> HOFF (own rows; h dead) ----------
    add_row32(sm, VOFF, tid, h);
    lnorm(h, ln1g + l * D, ln1b + l * D);
    store_h16(sm, tid, h);
    wave_fence();

    // ---- fused GEMM3+GEMM4 (t in registers, r5-verified); h' from HOFF ---
    {
      const float* Wa = w1 + l * DFF * D;
      const float* Ba = b1 + l * DFF;
      const float* Wb = w2 + l * D * DFF;
      const float* Bb = b2 + l * D;
      h8 WaF[4]; f4 ba4[4]; h8 WbF[4]; f4 bb2[2];
#pragma unroll
      for (int ft = 0; ft < 4; ++ft) {
        ba4[ft] = *(const f4*)(Ba + ft * 16 + quad * 4);
        WaF[ft] = bfrag8(Wa, ft * 16 + n16, quad);
      }
#pragma unroll
      for (int nt = 0; nt < 2; ++nt) {
        bb2[nt] = *(const f4*)(Bb + nt * 16 + quad * 4);
#pragma unroll
        for (int g = 0; g < 2; ++g)
          WbF[nt * 2 + g] = hcat(bfrag(Wb, nt * 16 + n16, 64, 2 * g, quad),
                                 bfrag(Wb, nt * 16 + n16, 64, 2 * g + 1, quad));
      }
#pragma unroll
      for (int tt = 0; tt < 4; ++tt) {
        const int tok = (wave * 4 + tt) * 16 + n16;
        const int rk = rkey(tok);
        h8 A8 = afrag8(sm, HOFF, tok, quad);
        h4 Pf[4];
#pragma unroll
        for (int ft = 0; ft < 4; ++ft) {
          f4 C = MFMA32(WaF[ft], A8, ba4[ft]);
          uint2 p{pk2(gelu(C[0]), gelu(C[1])), pk2(gelu(C[2]), gelu(C[3]))};
          Pf[ft] = __builtin_bit_cast(h4, p);
        }
        h8 P8a = hcat(Pf[0], Pf[1]);
        h8 P8b = hcat(Pf[2], Pf[3]);
#pragma unroll
        for (int nt = 0; nt < 2; ++nt) {
          f4 C = MFMA32(WbF[nt * 2], P8a, bb2[nt]);
          C = MFMA32(WbF[nt * 2 + 1], P8b, C);
          uint2 p{pk2(C[0], C[1]), pk2(C[2], C[3])};
          *(uint2*)(sm + VOFF + tok * 64 + (((nt * 4 + quad) ^ rk) * 8)) = p;
        }
      }
    }
    wave_fence();  // O'' rows are own-wave

    // ---- token: h += O''; LN2; h f16 -> HOFF (next layer's ph1 src) ------
    add_row32(sm, VOFF, tid, h);
    lnorm(h, ln2g + l * D, ln2b + l * D);
    if (l < NL - 1) store_h16(sm, tid, h);  // dead after last layer
  }

  // ---------- final LN + head ----------
  __syncthreads();  // staging overlays HOFF+VOFF still read by other waves
  lnorm(h, nog, nob);
  float* hs = (float*)sm;  // 25.6 KB staging over dead HOFF+VOFF
#pragma unroll
  for (int o = 0; o < HOUT; ++o)
    hs[tid * HOUT + o] = dotp<16>(hw + o * D, h) + hb[o];
  __syncthreads();
  f2* og = (f2*)(out + blk_tok * HOUT);
  const f2* os2 = (const f2*)hs;
  for (int i = tid; i < S * HOUT / 2; i += TPB) og[i] = os2[i];
}

extern "C" void kernel_launch(void* const* d_in, const int* in_sizes, int n_in,
                              void* d_out, int out_size, void* d_ws, size_t ws_size,
                              hipStream_t stream) {
  const float* x    = (const float*)d_in[0];
  const int*   lays = (const int*)  d_in[1];
  const float* fpw  = (const float*)d_in[2];
  const float* fpb  = (const float*)d_in[3];
  const float* lemb = (const float*)d_in[4];
  const float* fB   = (const float*)d_in[5];
  const float* ipw  = (const float*)d_in[6];
  const float* ipb  = (const float*)d_in[7];
  const float* opw  = (const float*)d_in[8];
  const float* opb  = (const float*)d_in[9];
  const float* ln1g = (const float*)d_in[10];
  const float* ln1b = (const float*)d_in[11];
  const float* w1   = (const float*)d_in[12];
  const float* b1   = (const float*)d_in[13];
  const float* w2   = (const float*)d_in[14];
  const float* b2   = (const float*)d_in[15];
  const float* ln2g = (const float*)d_in[16];
  const float* ln2b = (const float*)d_in[17];
  const float* nog  = (const float*)d_in[18];
  const float* nob  = (const float*)d_in[19];
  const float* hw   = (const float*)d_in[20];
  const float* hb   = (const float*)d_in[21];
  float* out = (float*)d_out;

  const int nwin = in_sizes[0] / (S * IND);  // 512 windows
  spai_fused<<<nwin, TPB, 0, stream>>>(x, lays, fpw, fpb, lemb, fB, ipw, ipb,
                                       opw, opb, ln1g, ln1b, w1, b1, w2, b2,
                                       ln2g, ln2b, nog, nob, hw, hb, out);
}

// Round 13
// 226.540 us; speedup vs baseline: 1.0200x; 1.0200x over previous
//
#include <hip/hip_runtime.h>

constexpr int S    = 256;
constexpr int D    = 32;
constexpr int NH   = 4;
constexpr int DH   = 8;
constexpr int DFF  = 64;
constexpr int NL   = 4;
constexpr int IND  = 58;
constexpr int HOUT = 25;
constexpr int TPB  = 256;  // 1 window/block, 4 waves; 2 blocks/CU (proven shell)
                           // 512-thread variants SPILL (round 3). Occupancy is
                           // GRID-capped (512 blk): do not chase occupancy.

typedef float  f2 __attribute__((ext_vector_type(2)));
typedef float  f4 __attribute__((ext_vector_type(4)));
typedef __fp16 h2 __attribute__((ext_vector_type(2)));
typedef __fp16 h4 __attribute__((ext_vector_type(4)));
typedef __fp16 h8 __attribute__((ext_vector_type(8)));

__device__ __forceinline__ f4 MFMA16(h4 a, h4 b, f4 c) {
  return __builtin_amdgcn_mfma_f32_16x16x16f16(a, b, c, 0, 0, 0);
}
// CDNA4-native K=32 shape. A/B frags = cat(K-half0, K-half1) on BOTH
// operands -> internal k-slot mapping cancels (layout-safe, r6-verified).
__device__ __forceinline__ f4 MFMA32(h8 a, h8 b, f4 c) {
  return __builtin_amdgcn_mfma_f32_16x16x32_f16(a, b, c, 0, 0, 0);
}
__device__ __forceinline__ h8 hcat(h4 a, h4 b) {
  return __builtin_shufflevector(a, b, 0, 1, 2, 3, 4, 5, 6, 7);
}

// LDS map (bytes), 32 KB. Liveness per layer:
//  HOFF: h f16 (ph1 src, all rows) -> h' f16 (G34 src, own rows)
//  VOFF: attn O (ph2 out, all rows) -> O'/O'' f16 (G2/G34 out, own rows)
constexpr int HOFF  = 0;      // 16 KB  [256][32] f16, 8B chunks ^rkey(tok)
constexpr int VOFF  = 16384;  // 16 KB  [256][32] f16, same swizzle
constexpr int LDSSZ = 32768;

// r12 swizzle key: (tok^(tok>>3))&7 — fixes the 8-way conflict the old
// (tok&7) key left in per-thread row paths (store_h16/add_row32/O-store):
// lanes with equal tok mod 8 hit one bank pair. Verified: SQ_LDS_BANK_
// CONFLICT 3.54M -> 655K (r12). Tile reads stay <=2-way (free).
__device__ __forceinline__ int rkey(int tok) { return (tok ^ (tok >> 3)) & 7; }

__device__ __forceinline__ unsigned pk2(float a, float b) {
  h2 h = __builtin_amdgcn_cvt_pkrtz(a, b);
  return __builtin_bit_cast(unsigned, h);
}

__device__ __forceinline__ float exp2fast(float x) {
#if __has_builtin(__builtin_amdgcn_exp2f)
  return __builtin_amdgcn_exp2f(x);   // v_exp_f32 = 2^x, one trans op
#else
  return exp2f(x);
#endif
}

// Compiler fence for same-wave LDS RAW (r9: wave_barrier only).
__device__ __forceinline__ void wave_fence() {
  __builtin_amdgcn_wave_barrier();
}

// packed-fp32 dot. All register-array loops must FULLY unroll (r3 lesson).
template<int NF2>
__device__ __forceinline__ float dotp(const float* __restrict__ w,
                                      const float* __restrict__ v) {
  const f2* W = (const f2*)w;
  const f2* V = (const f2*)v;
  f2 a0 = {0.f, 0.f}, a1 = {0.f, 0.f};
#pragma unroll
  for (int i = 0; i < NF2; i += 2) a0 += V[i] * W[i];
#pragma unroll
  for (int i = 1; i < NF2; i += 2) a1 += V[i] * W[i];
  f2 s = a0 + a1;
  return s.x + s.y;
}

// tanh-approx GELU via exp2 (log2e folded; verified family r7-r10)
__device__ __forceinline__ float gelu(float x) {
  float u = 2.3022082f * fmaf(0.044715f * x * x, x, x);  // 1.59576912*log2(e)
  return x * __builtin_amdgcn_rcpf(1.0f + exp2fast(-u));
}

// LayerNorm on 32 f32 regs, packed-f32 (v_pk_*) form.
__device__ __forceinline__ void lnorm(float* h, const float* __restrict__ g,
                                      const float* __restrict__ b) {
  f2* hv = (f2*)h;
  f2 s0 = hv[0], s1 = hv[1];
#pragma unroll
  for (int i = 2; i < 16; i += 2) { s0 += hv[i]; s1 += hv[i + 1]; }
  f2 s = s0 + s1;
  const float m = (s.x + s.y) * (1.0f / D);
  const f2 m2 = {m, m};
  f2 v0 = {0.f, 0.f}, v1 = {0.f, 0.f};
#pragma unroll
  for (int i = 0; i < 16; i += 2) {
    f2 c0 = hv[i] - m2;     v0 += c0 * c0;
    f2 c1 = hv[i + 1] - m2; v1 += c1 * c1;
  }
  f2 vs = v0 + v1;
  const float inv = __builtin_amdgcn_rsqf((vs.x + vs.y) * (1.0f / D) + 1e-5f);
  const f2 inv2 = {inv, inv};
  const f2 mi2 = {-m * inv, -m * inv};
  const f2* g2 = (const f2*)g;
  const f2* b2 = (const f2*)b;
#pragma unroll
  for (int i = 0; i < 16; ++i) {
    f2 t = hv[i] * inv2 + mi2;   // (h-m)*inv  as pk_fma
    hv[i] = t * g2[i] + b2[i];   // *g + b     as pk_fma
  }
}

__device__ __forceinline__ void embed_token(
    const float* __restrict__ xrow, int lay,
    const float* __restrict__ fpw, const float* __restrict__ fpb,
    const float* __restrict__ lemb, const float* __restrict__ fB,
    float* __restrict__ h) {
  float xr[IND];
  const f2* xv = (const f2*)xrow;
#pragma unroll
  for (int i = 0; i < 29; ++i) { f2 t = xv[i]; xr[2 * i] = t.x; xr[2 * i + 1] = t.y; }
  const float* le = lemb + lay * D;
  float pe[D];
#pragma unroll
  for (int k = 0; k < 16; ++k) {
    // sin(2*pi*t) = v_sin(fract(t)) in revolutions (verified r9/r10)
    float t = xr[0] * fB[k] + xr[1] * fB[16 + k] + xr[2] * fB[32 + k];
#if __has_builtin(__builtin_amdgcn_sinf) && __has_builtin(__builtin_amdgcn_cosf) && __has_builtin(__builtin_amdgcn_fractf)
    float u = __builtin_amdgcn_fractf(t);
    pe[k]      = __builtin_amdgcn_sinf(u);
    pe[16 + k] = __builtin_amdgcn_cosf(u);
#else
    float sv, cv;
    sincosf(6.2831853071795864f * (t - floorf(t)), &sv, &cv);
    pe[k] = sv; pe[16 + k] = cv;
#endif
  }
#pragma unroll
  for (int d = 0; d < D; ++d)
    h[d] = dotp<29>(fpw + d * IND, xr) + fpb[d] + le[d] + pe[d];
}

// ---- shared fragment helpers (layouts verified r8/r11; key r12) ----
__device__ __forceinline__ h4 bfrag(const float* __restrict__ W, int row,
                                    int K, int kh, int quad) {
  f4 w = *(const f4*)(W + row * K + kh * 16 + quad * 4);
  uint2 p{pk2(w.x, w.y), pk2(w.z, w.w)};
  return __builtin_bit_cast(h4, p);
}
__device__ __forceinline__ h8 bfrag8(const float* __restrict__ W, int row,
                                     int quad) {
  return hcat(bfrag(W, row, 32, 0, quad), bfrag(W, row, 32, 1, quad));
}
// K=32 weight row with scale folded (for QKV weight frags)
__device__ __forceinline__ h8 wfrag8(const float* __restrict__ W, int row,
                                     int quad, float sc) {
  f4 w0 = *(const f4*)(W + row * D + quad * 4) * sc;
  f4 w1 = *(const f4*)(W + row * D + 16 + quad * 4) * sc;
  uint2 p0{pk2(w0.x, w0.y), pk2(w0.z, w0.w)};
  uint2 p1{pk2(w1.x, w1.y), pk2(w1.z, w1.w)};
  return hcat(__builtin_bit_cast(h4, p0), __builtin_bit_cast(h4, p1));
}
// token frag from [tok][32] f16, 8B chunks swizzled ^rkey(tok)
__device__ __forceinline__ h4 afrag32(const unsigned char* sm, int base,
                                      int tok, int kh, int quad) {
  return *(const h4*)(sm + base + tok * 64 + (((kh * 4 + quad) ^ rkey(tok)) * 8));
}
__device__ __forceinline__ h8 afrag8(const unsigned char* sm, int base,
                                     int tok, int quad) {
  return hcat(afrag32(sm, base, tok, 0, quad), afrag32(sm, base, tok, 1, quad));
}

// Write this thread's h (f32 regs) as swizzled f16 row into HOFF.
__device__ __forceinline__ void store_h16(unsigned char* sm, int tok,
                                          const float* __restrict__ h) {
  const int k = rkey(tok);
#pragma unroll
  for (int c = 0; c < 8; ++c) {
    uint2 p{pk2(h[4 * c], h[4 * c + 1]), pk2(h[4 * c + 2], h[4 * c + 3])};
    *(uint2*)(sm + HOFF + tok * 64 + ((c ^ k) * 8)) = p;
  }
}
// Read a swizzled [tok][32] f16 row, accumulate into h (residual add).
__device__ __forceinline__ void add_row32(const unsigned char* sm, int base,
                                          int tok, float* __restrict__ h) {
  f2* hv = (f2*)h;
  const int k = rkey(tok);
#pragma unroll
  for (int c = 0; c < 8; ++c) {
    h4 q = *(const h4*)(sm + base + tok * 64 + ((c ^ k) * 8));
    f2 lo = {(float)q[0], (float)q[1]};
    f2 hi = {(float)q[2], (float)q[3]};
    hv[2 * c] += lo;
    hv[2 * c + 1] += hi;
  }
}

// launch_bounds: ONLY (256,2) is spill-free for this family (r5-r10, round 3).
__global__ void __launch_bounds__(TPB, 2)
spai_fused(const float* __restrict__ x,    const int*   __restrict__ layers,
           const float* __restrict__ fpw,  const float* __restrict__ fpb,
           const float* __restrict__ lemb, const float* __restrict__ fB,
           const float* __restrict__ ipw,  const float* __restrict__ ipb,
           const float* __restrict__ opw,  const float* __restrict__ opb,
           const float* __restrict__ ln1g, const float* __restrict__ ln1b,
           const float* __restrict__ w1,   const float* __restrict__ b1,
           const float* __restrict__ w2,   const float* __restrict__ b2,
           const float* __restrict__ ln2g, const float* __restrict__ ln2b,
           const float* __restrict__ nog,  const float* __restrict__ nob,
           const float* __restrict__ hw,   const float* __restrict__ hb,
           float* __restrict__ out) {
  __shared__ __align__(16) unsigned char sm[LDSSZ];
  const int tid    = threadIdx.x;
  const int lane   = tid & 63;
  const int wave   = tid >> 6;   // 0..3 == head index
  const int n16    = lane & 15;
  const int quad   = lane >> 4;
  const int pairi  = wave >> 1;  // head pair {0,1} / {2,3}
  const int parity = wave & 1;   // head = 2*pairi + parity
  const size_t blk_tok = (size_t)blockIdx.x * S;

  float h[D];
  embed_token(x + (blk_tok + tid) * IND, layers[blk_tok + tid],
              fpw, fpb, lemb, fB, h);
  store_h16(sm, tid, h);   // published by barrier A (l=0)

  for (int l = 0; l < NL; ++l) {
    // Barrier A: h stores (own rows) -> ph1 h reads (all rows); also
    // separates prev-layer VOFF readers from this layer's ph2 O writes.
    __syncthreads();

    const float* Wi = ipw + l * (3 * D) * D;
    const float* Bi = ipb + l * (3 * D);

    // ---- ph1: per-wave head-pair QKV over ALL 16 token tiles -------------
    // Pair waves duplicate this. C-frags ARE ph2's operand frags; handoff is
    // SAME-THREAD -> Q/K/V all live in registers (r10). Odd head's V via
    // weight-row XOR 8 (bit-identical to shfl). Q pre-scaled by
    // (1/sqrt(dh))*log2e; other head's Q half zeroed once at creation.
    h4 Kf[16], Vf[16], Qf[16];
    {
      const float scq = 0.51006973f;  // 0.35355339 * log2(e)
      h8 BfQ = wfrag8(Wi, pairi * 16 + n16, quad, scq);
      h8 BfK = wfrag8(Wi + 32 * D, pairi * 16 + n16, quad, 1.0f);
      const int vrow = pairi * 16 + (n16 ^ (parity << 3));
      h8 BfV = wfrag8(Wi + 64 * D, vrow, quad, 1.0f);
      f4 bq = *(const f4*)(Bi + pairi * 16 + quad * 4) * scq;
      f4 bk = *(const f4*)(Bi + 32 + pairi * 16 + quad * 4);
      const float bvv = Bi[64 + vrow];
      const f4 bv4 = {bvv, bvv, bvv, bvv};
      const unsigned fill = (n16 == 8) ? 0x3C003C00u : 0u;  // lsum ones row
      const bool qlive = (quad >> 1) == parity;
#pragma unroll
      for (int it = 0; it < 16; ++it) {
        const int tok = it * 16 + n16;
        h8 Ah = afrag8(sm, HOFF, tok, quad);
        f4 Cq = MFMA32(BfQ, Ah, bq);   // col n16 = token, row quad*4+r = feat
        f4 Ck = MFMA32(BfK, Ah, bk);
        f4 Cv = MFMA32(Ah, BfV, bv4);  // col n16 = feat, C[r] = token quad*4+r
        uint2 q{pk2(Cq[0], Cq[1]), pk2(Cq[2], Cq[3])};
        if (!qlive) { q.x = 0u; q.y = 0u; }  // zero other head's k-half
        Qf[it] = __builtin_bit_cast(h4, q);
        uint2 kk{pk2(Ck[0], Ck[1]), pk2(Ck[2], Ck[3])};
        Kf[it] = __builtin_bit_cast(h4, kk);
        uint2 v{pk2(Cv[0], Cv[1]), pk2(Cv[2], Cv[3])};
        if (n16 >= 8) { v.x = fill; v.y = fill; }  // row 8 ones, 9-15 zero
        Vf[it] = __builtin_bit_cast(h4, v);
      }
    }
    // No fence: ph1->ph2 is pure register dataflow.

    // ---- ph2: flash attention (wave = head), QKV fully in registers ------
    // r11 pipeline shape (proven spill-free at VGPR 116): V8 pairs prebuilt;
    // QK^T software-pipelined WITHIN each it (next j2's T MFMAs issue before
    // current j2's exp block). r13: across-it prefetch REVERTED — it pushed
    // VGPR to 128 and spilled ~5.6MB scratch (r12 WRITE_SIZE 12800->18432),
    // eating the rkey win. rkey swizzle kept (conflicts 3.54M->655K).
    {
      const int hh  = wave;
      const int m   = n16;
      const int obase = hh * 2 + quad;    // O feat-block (valid quad<2)
      const f4 Z = {0.f, 0.f, 0.f, 0.f};
      h8 V8a[8];
#pragma unroll
      for (int j2 = 0; j2 < 8; ++j2) V8a[j2] = hcat(Vf[2 * j2], Vf[2 * j2 + 1]);
      __builtin_amdgcn_s_setprio(1);
#pragma unroll
      for (int it = 0; it < 16; ++it) {
        const int ti = it * 16 + m;
        h4 Q4 = Qf[it];
        f4 Of0 = Z, Of1 = Z;
        f4 T0 = MFMA16(Kf[0], Q4, Z);
        f4 T1 = MFMA16(Kf[1], Q4, Z);
#pragma unroll
        for (int j2 = 0; j2 < 8; ++j2) {
          f4 nT0 = T0, nT1 = T1;
          if (j2 < 7) {  // prefetch next tile-pair's scores
            nT0 = MFMA16(Kf[2 * j2 + 2], Q4, Z);
            nT1 = MFMA16(Kf[2 * j2 + 3], Q4, Z);
          }
          uint2 pa{pk2(exp2fast(T0[0]), exp2fast(T0[1])),
                   pk2(exp2fast(T0[2]), exp2fast(T0[3]))};
          uint2 pb{pk2(exp2fast(T1[0]), exp2fast(T1[1])),
                   pk2(exp2fast(T1[2]), exp2fast(T1[3]))};
          h8 P8 = hcat(__builtin_bit_cast(h4, pa), __builtin_bit_cast(h4, pb));
          if (j2 & 1) Of1 = MFMA32(V8a[j2], P8, Of1);
          else        Of0 = MFMA32(V8a[j2], P8, Of0);
          T0 = nT0; T1 = nT1;
        }
        f4 Of = Of0 + Of1;
        // C row 8 (quad==2, elem 0) = softmax denominator (lsum trick)
        float rinv = __builtin_amdgcn_rcpf(Of[0]);
        rinv = __builtin_bit_cast(
            float, __builtin_amdgcn_ds_bpermute(
                       (32 + m) << 2, __builtin_bit_cast(int, rinv)));
        if (quad < 2) {  // rows 0..7 = O features hh*8+quad*4+r of token ti
          f4 o = Of * rinv;
          uint2 p{pk2(o[0], o[1]), pk2(o[2], o[3])};
          *(uint2*)(sm + VOFF + ti * 64 + ((obase ^ rkey(ti)) * 8)) = p;
        }
      }
      __builtin_amdgcn_s_setprio(0);
    }
    // Barrier B: O (cross-head chunks, VOFF) visible to all; also all ph1
    // h-reads finished -> HOFF rows reusable below.
    __syncthreads();

    // ---- GEMM2: O'^T = Wo x O^T; read VOFF, write VOFF own rows ----------
    // (read-then-write same row by same lane, DS in-order within wave)
    {
      const float* Wo = opw + l * D * D;
      const float* Bo = opb + l * D;
      h8 WoF[2]; f4 bo2[2];
#pragma unroll
      for (int nt = 0; nt < 2; ++nt) {
        bo2[nt] = *(const f4*)(Bo + nt * 16 + quad * 4);
        WoF[nt] = bfrag8(Wo, nt * 16 + n16, quad);
      }
#pragma unroll
      for (int ii = 0; ii < 4; ++ii) {
        const int tok = (wave * 4 + ii) * 16 + n16;
        const int rk = rkey(tok);
        h8 A8 = afrag8(sm, VOFF, tok, quad);
#pragma unroll
        for (int nt = 0; nt < 2; ++nt) {
          f4 C = MFMA32(WoF[nt], A8, bo2[nt]);
          uint2 p{pk2(C[0], C[1]), pk2(C[2], C[3])};
          *(uint2*)(sm + VOFF + tok * 64 + (((nt * 4 + quad) ^ rk) * 8)) = p;
        }
      }
    }
    wave_fence();  // O' rows are own-wave

    // ---- token: h += O'; LN1; h' f16 -> HOFF (own rows; h dead) ----------
    add_row32(sm, VOFF, tid, h);
    lnorm(h, ln1g + l * D, ln1b + l * D);
    store_h16(sm, tid, h);
    wave_fence();

    // ---- fused GEMM3+GEMM4 (t in registers, r5-verified); h' from HOFF ---
    {
      const float* Wa = w1 + l * DFF * D;
      const float* Ba = b1 + l * DFF;
      const float* Wb = w2 + l * D * DFF;
      const float* Bb = b2 + l * D;
      h8 WaF[4]; f4 ba4[4]; h8 WbF[4]; f4 bb2[2];
#pragma unroll
      for (int ft = 0; ft < 4; ++ft) {
        ba4[ft] = *(const f4*)(Ba + ft * 16 + quad * 4);
        WaF[ft] = bfrag8(Wa, ft * 16 + n16, quad);
      }
#pragma unroll
      for (int nt = 0; nt < 2; ++nt) {
        bb2[nt] = *(const f4*)(Bb + nt * 16 + quad * 4);
#pragma unroll
        for (int g = 0; g < 2; ++g)
          WbF[nt * 2 + g] = hcat(bfrag(Wb, nt * 16 + n16, 64, 2 * g, quad),
                                 bfrag(Wb, nt * 16 + n16, 64, 2 * g + 1, quad));
      }
#pragma unroll
      for (int tt = 0; tt < 4; ++tt) {
        const int tok = (wave * 4 + tt) * 16 + n16;
        const int rk = rkey(tok);
        h8 A8 = afrag8(sm, HOFF, tok, quad);
        h4 Pf[4];
#pragma unroll
        for (int ft = 0; ft < 4; ++ft) {
          f4 C = MFMA32(WaF[ft], A8, ba4[ft]);
          uint2 p{pk2(gelu(C[0]), gelu(C[1])), pk2(gelu(C[2]), gelu(C[3]))};
          Pf[ft] = __builtin_bit_cast(h4, p);
        }
        h8 P8a = hcat(Pf[0], Pf[1]);
        h8 P8b = hcat(Pf[2], Pf[3]);
#pragma unroll
        for (int nt = 0; nt < 2; ++nt) {
          f4 C = MFMA32(WbF[nt * 2], P8a, bb2[nt]);
          C = MFMA32(WbF[nt * 2 + 1], P8b, C);
          uint2 p{pk2(C[0], C[1]), pk2(C[2], C[3])};
          *(uint2*)(sm + VOFF + tok * 64 + (((nt * 4 + quad) ^ rk) * 8)) = p;
        }
      }
    }
    wave_fence();  // O'' rows are own-wave

    // ---- token: h += O''; LN2; h f16 -> HOFF (next layer's ph1 src) ------
    add_row32(sm, VOFF, tid, h);
    lnorm(h, ln2g + l * D, ln2b + l * D);
    if (l < NL - 1) store_h16(sm, tid, h);  // dead after last layer
  }

  // ---------- final LN + head ----------
  __syncthreads();  // staging overlays HOFF+VOFF still read by other waves
  lnorm(h, nog, nob);
  float* hs = (float*)sm;  // 25.6 KB staging over dead HOFF+VOFF
#pragma unroll
  for (int o = 0; o < HOUT; ++o)
    hs[tid * HOUT + o] = dotp<16>(hw + o * D, h) + hb[o];
  __syncthreads();
  f2* og = (f2*)(out + blk_tok * HOUT);
  const f2* os2 = (const f2*)hs;
  for (int i = tid; i < S * HOUT / 2; i += TPB) og[i] = os2[i];
}

extern "C" void kernel_launch(void* const* d_in, const int* in_sizes, int n_in,
                              void* d_out, int out_size, void* d_ws, size_t ws_size,
                              hipStream_t stream) {
  const float* x    = (const float*)d_in[0];
  const int*   lays = (const int*)  d_in[1];
  const float* fpw  = (const float*)d_in[2];
  const float* fpb  = (const float*)d_in[3];
  const float* lemb = (const float*)d_in[4];
  const float* fB   = (const float*)d_in[5];
  const float* ipw  = (const float*)d_in[6];
  const float* ipb  = (const float*)d_in[7];
  const float* opw  = (const float*)d_in[8];
  const float* opb  = (const float*)d_in[9];
  const float* ln1g = (const float*)d_in[10];
  const float* ln1b = (const float*)d_in[11];
  const float* w1   = (const float*)d_in[12];
  const float* b1   = (const float*)d_in[13];
  const float* w2   = (const float*)d_in[14];
  const float* b2   = (const float*)d_in[15];
  const float* ln2g = (const float*)d_in[16];
  const float* ln2b = (const float*)d_in[17];
  const float* nog  = (const float*)d_in[18];
  const float* nob  = (const float*)d_in[19];
  const float* hw   = (const float*)d_in[20];
  const float* hb   = (const float*)d_in[21];
  float* out = (float*)d_out;

  const int nwin = in_sizes[0] / (S * IND);  // 512 windows
  spai_fused<<<nwin, TPB, 0, stream>>>(x, lays, fpw, fpb, lemb, fB, ipw, ipb,
                                       opw, opb, ln1g, ln1b, w1, b1, w2, b2,
                                       ln2g, ln2b, nog, nob, hw, hb, out);
}

// Round 14
// 220.156 us; speedup vs baseline: 1.0496x; 1.0290x over previous
//
#include <hip/hip_runtime.h>

constexpr int S    = 256;
constexpr int D    = 32;
constexpr int NH   = 4;
constexpr int DH   = 8;
constexpr int DFF  = 64;
constexpr int NL   = 4;
constexpr int IND  = 58;
constexpr int HOUT = 25;
constexpr int TPB  = 256;  // 1 window/block, 4 waves; 2 blocks/CU (proven shell)
                           // 512-thread variants SPILL (round 3). Occupancy is
                           // GRID-capped (512 blk): do not chase occupancy.

typedef float  f2 __attribute__((ext_vector_type(2)));
typedef float  f4 __attribute__((ext_vector_type(4)));
typedef __fp16 h2 __attribute__((ext_vector_type(2)));
typedef __fp16 h4 __attribute__((ext_vector_type(4)));
typedef __fp16 h8 __attribute__((ext_vector_type(8)));

__device__ __forceinline__ f4 MFMA16(h4 a, h4 b, f4 c) {
  return __builtin_amdgcn_mfma_f32_16x16x16f16(a, b, c, 0, 0, 0);
}
// CDNA4-native K=32 shape. A/B frags = cat(K-half0, K-half1) on BOTH
// operands -> internal k-slot mapping cancels (layout-safe, r6-verified).
__device__ __forceinline__ f4 MFMA32(h8 a, h8 b, f4 c) {
  return __builtin_amdgcn_mfma_f32_16x16x32_f16(a, b, c, 0, 0, 0);
}
__device__ __forceinline__ h8 hcat(h4 a, h4 b) {
  return __builtin_shufflevector(a, b, 0, 1, 2, 3, 4, 5, 6, 7);
}

// LDS map (bytes), 32 KB. Liveness per layer:
//  HOFF: h f16 (ph1 src, all rows) -> h' f16 (G34 src, own rows)
//  VOFF: attn O (ph2 out, all rows) -> O'/O'' f16 (G2/G34 out, own rows)
constexpr int HOFF  = 0;      // 16 KB  [256][32] f16, 8B chunks ^key(tok)
constexpr int VOFF  = 16384;  // 16 KB  [256][32] f16, same swizzle
constexpr int LDSSZ = 32768;

// Swizzle key (r12 semantics, r14 decomposed form):
//   key(tok) = (tok ^ (tok>>3)) & 7  — kills the 8-way bank conflict of the
//   old (tok&7) key in per-thread row paths (conflicts 3.54M->655K, r12).
// r13 lesson: computing key(tok) AT USE with tok=it*16+m makes the compiler
// materialize 16 live address temps -> 5MB scratch spill (WRITE 12800->17920,
// VGPR 116->128). DECOMPOSITION (this round): for tok = X*16 + m,
//   key = bk16 ^ ((2X)&7),  bk16 = (m&7)^(m>>3)   [2X even => &7 splits]
// In unrolled loops (2X)&7 is a COMPILE-TIME immediate (X=it; or X=wave*4+ii
// => (2X)&7=(2ii)&7); per-thread paths compute it once (X=tid>>4). Zero
// extra live registers.

__device__ __forceinline__ unsigned pk2(float a, float b) {
  h2 h = __builtin_amdgcn_cvt_pkrtz(a, b);
  return __builtin_bit_cast(unsigned, h);
}

__device__ __forceinline__ float exp2fast(float x) {
#if __has_builtin(__builtin_amdgcn_exp2f)
  return __builtin_amdgcn_exp2f(x);   // v_exp_f32 = 2^x, one trans op
#else
  return exp2f(x);
#endif
}

// Compiler fence for same-wave LDS RAW (r9: wave_barrier only).
__device__ __forceinline__ void wave_fence() {
  __builtin_amdgcn_wave_barrier();
}

// packed-fp32 dot. All register-array loops must FULLY unroll (r3 lesson).
template<int NF2>
__device__ __forceinline__ float dotp(const float* __restrict__ w,
                                      const float* __restrict__ v) {
  const f2* W = (const f2*)w;
  const f2* V = (const f2*)v;
  f2 a0 = {0.f, 0.f}, a1 = {0.f, 0.f};
#pragma unroll
  for (int i = 0; i < NF2; i += 2) a0 += V[i] * W[i];
#pragma unroll
  for (int i = 1; i < NF2; i += 2) a1 += V[i] * W[i];
  f2 s = a0 + a1;
  return s.x + s.y;
}

// tanh-approx GELU via exp2 (log2e folded; verified family r7-r10)
__device__ __forceinline__ float gelu(float x) {
  float u = 2.3022082f * fmaf(0.044715f * x * x, x, x);  // 1.59576912*log2(e)
  return x * __builtin_amdgcn_rcpf(1.0f + exp2fast(-u));
}

// LayerNorm on 32 f32 regs, packed-f32 (v_pk_*) form.
__device__ __forceinline__ void lnorm(float* h, const float* __restrict__ g,
                                      const float* __restrict__ b) {
  f2* hv = (f2*)h;
  f2 s0 = hv[0], s1 = hv[1];
#pragma unroll
  for (int i = 2; i < 16; i += 2) { s0 += hv[i]; s1 += hv[i + 1]; }
  f2 s = s0 + s1;
  const float m = (s.x + s.y) * (1.0f / D);
  const f2 m2 = {m, m};
  f2 v0 = {0.f, 0.f}, v1 = {0.f, 0.f};
#pragma unroll
  for (int i = 0; i < 16; i += 2) {
    f2 c0 = hv[i] - m2;     v0 += c0 * c0;
    f2 c1 = hv[i + 1] - m2; v1 += c1 * c1;
  }
  f2 vs = v0 + v1;
  const float inv = __builtin_amdgcn_rsqf((vs.x + vs.y) * (1.0f / D) + 1e-5f);
  const f2 inv2 = {inv, inv};
  const f2 mi2 = {-m * inv, -m * inv};
  const f2* g2 = (const f2*)g;
  const f2* b2 = (const f2*)b;
#pragma unroll
  for (int i = 0; i < 16; ++i) {
    f2 t = hv[i] * inv2 + mi2;   // (h-m)*inv  as pk_fma
    hv[i] = t * g2[i] + b2[i];   // *g + b     as pk_fma
  }
}

__device__ __forceinline__ void embed_token(
    const float* __restrict__ xrow, int lay,
    const float* __restrict__ fpw, const float* __restrict__ fpb,
    const float* __restrict__ lemb, const float* __restrict__ fB,
    float* __restrict__ h) {
  float xr[IND];
  const f2* xv = (const f2*)xrow;
#pragma unroll
  for (int i = 0; i < 29; ++i) { f2 t = xv[i]; xr[2 * i] = t.x; xr[2 * i + 1] = t.y; }
  const float* le = lemb + lay * D;
  float pe[D];
#pragma unroll
  for (int k = 0; k < 16; ++k) {
    // sin(2*pi*t) = v_sin(fract(t)) in revolutions (verified r9/r10)
    float t = xr[0] * fB[k] + xr[1] * fB[16 + k] + xr[2] * fB[32 + k];
#if __has_builtin(__builtin_amdgcn_sinf) && __has_builtin(__builtin_amdgcn_cosf) && __has_builtin(__builtin_amdgcn_fractf)
    float u = __builtin_amdgcn_fractf(t);
    pe[k]      = __builtin_amdgcn_sinf(u);
    pe[16 + k] = __builtin_amdgcn_cosf(u);
#else
    float sv, cv;
    sincosf(6.2831853071795864f * (t - floorf(t)), &sv, &cv);
    pe[k] = sv; pe[16 + k] = cv;
#endif
  }
#pragma unroll
  for (int d = 0; d < D; ++d)
    h[d] = dotp<29>(fpw + d * IND, xr) + fpb[d] + le[d] + pe[d];
}

// ---- shared fragment helpers (layouts verified r8/r11; key r12/r14) ----
__device__ __forceinline__ h4 bfrag(const float* __restrict__ W, int row,
                                    int K, int kh, int quad) {
  f4 w = *(const f4*)(W + row * K + kh * 16 + quad * 4);
  uint2 p{pk2(w.x, w.y), pk2(w.z, w.w)};
  return __builtin_bit_cast(h4, p);
}
__device__ __forceinline__ h8 bfrag8(const float* __restrict__ W, int row,
                                     int quad) {
  return hcat(bfrag(W, row, 32, 0, quad), bfrag(W, row, 32, 1, quad));
}
// K=32 weight row with scale folded (for QKV weight frags)
__device__ __forceinline__ h8 wfrag8(const float* __restrict__ W, int row,
                                     int quad, float sc) {
  f4 w0 = *(const f4*)(W + row * D + quad * 4) * sc;
  f4 w1 = *(const f4*)(W + row * D + 16 + quad * 4) * sc;
  uint2 p0{pk2(w0.x, w0.y), pk2(w0.z, w0.w)};
  uint2 p1{pk2(w1.x, w1.y), pk2(w1.z, w1.w)};
  return hcat(__builtin_bit_cast(h4, p0), __builtin_bit_cast(h4, p1));
}
// token frag from [tok][32] f16, 8B chunks ^key (key passed precomputed)
__device__ __forceinline__ h8 afrag8k(const unsigned char* sm, int base,
                                      int tok, int quad, int key) {
  const h4 a = *(const h4*)(sm + base + tok * 64 + ((quad ^ key) * 8));
  const h4 b = *(const h4*)(sm + base + tok * 64 + (((4 + quad) ^ key) * 8));
  return hcat(a, b);
}

// Write this thread's h (f32 regs) as swizzled f16 row (key precomputed).
__device__ __forceinline__ void store_h16(unsigned char* sm, int tok, int key,
                                          const float* __restrict__ h) {
#pragma unroll
  for (int c = 0; c < 8; ++c) {
    uint2 p{pk2(h[4 * c], h[4 * c + 1]), pk2(h[4 * c + 2], h[4 * c + 3])};
    *(uint2*)(sm + HOFF + tok * 64 + ((c ^ key) * 8)) = p;
  }
}
// Read a swizzled [tok][32] f16 row, accumulate into h (residual add).
__device__ __forceinline__ void add_row32(const unsigned char* sm, int base,
                                          int tok, int key, float* __restrict__ h) {
  f2* hv = (f2*)h;
#pragma unroll
  for (int c = 0; c < 8; ++c) {
    h4 q = *(const h4*)(sm + base + tok * 64 + ((c ^ key) * 8));
    f2 lo = {(float)q[0], (float)q[1]};
    f2 hi = {(float)q[2], (float)q[3]};
    hv[2 * c] += lo;
    hv[2 * c + 1] += hi;
  }
}

// launch_bounds: ONLY (256,2) is spill-free for this family (r5-r10, round 3).
__global__ void __launch_bounds__(TPB, 2)
spai_fused(const float* __restrict__ x,    const int*   __restrict__ layers,
           const float* __restrict__ fpw,  const float* __restrict__ fpb,
           const float* __restrict__ lemb, const float* __restrict__ fB,
           const float* __restrict__ ipw,  const float* __restrict__ ipb,
           const float* __restrict__ opw,  const float* __restrict__ opb,
           const float* __restrict__ ln1g, const float* __restrict__ ln1b,
           const float* __restrict__ w1,   const float* __restrict__ b1,
           const float* __restrict__ w2,   const float* __restrict__ b2,
           const float* __restrict__ ln2g, const float* __restrict__ ln2b,
           const float* __restrict__ nog,  const float* __restrict__ nob,
           const float* __restrict__ hw,   const float* __restrict__ hb,
           float* __restrict__ out) {
  __shared__ __align__(16) unsigned char sm[LDSSZ];
  const int tid    = threadIdx.x;
  const int lane   = tid & 63;
  const int wave   = tid >> 6;   // 0..3 == head index
  const int n16    = lane & 15;
  const int quad   = lane >> 4;
  const int pairi  = wave >> 1;  // head pair {0,1} / {2,3}
  const int parity = wave & 1;   // head = 2*pairi + parity
  const int bk16   = (n16 & 7) ^ (n16 >> 3);           // per-lane key base
  const int hk     = bk16 ^ ((2 * (tid >> 4)) & 7);    // key(tid), row paths
  const size_t blk_tok = (size_t)blockIdx.x * S;

  float h[D];
  embed_token(x + (blk_tok + tid) * IND, layers[blk_tok + tid],
              fpw, fpb, lemb, fB, h);
  store_h16(sm, tid, hk, h);   // published by barrier A (l=0)

  for (int l = 0; l < NL; ++l) {
    // Barrier A: h stores (own rows) -> ph1 h reads (all rows); also
    // separates prev-layer VOFF readers from this layer's ph2 O writes.
    __syncthreads();

    const float* Wi = ipw + l * (3 * D) * D;
    const float* Bi = ipb + l * (3 * D);

    // ---- ph1: per-wave head-pair QKV over ALL 16 token tiles -------------
    // Pair waves duplicate this. C-frags ARE ph2's operand frags; handoff is
    // SAME-THREAD -> Q/K/V all live in registers (r10). Odd head's V via
    // weight-row XOR 8 (bit-identical to shfl). Q pre-scaled by
    // (1/sqrt(dh))*log2e; other head's Q half zeroed once at creation.
    h4 Kf[16], Vf[16], Qf[16];
    {
      const float scq = 0.51006973f;  // 0.35355339 * log2(e)
      h8 BfQ = wfrag8(Wi, pairi * 16 + n16, quad, scq);
      h8 BfK = wfrag8(Wi + 32 * D, pairi * 16 + n16, quad, 1.0f);
      const int vrow = pairi * 16 + (n16 ^ (parity << 3));
      h8 BfV = wfrag8(Wi + 64 * D, vrow, quad, 1.0f);
      f4 bq = *(const f4*)(Bi + pairi * 16 + quad * 4) * scq;
      f4 bk = *(const f4*)(Bi + 32 + pairi * 16 + quad * 4);
      const float bvv = Bi[64 + vrow];
      const f4 bv4 = {bvv, bvv, bvv, bvv};
      const unsigned fill = (n16 == 8) ? 0x3C003C00u : 0u;  // lsum ones row
      const bool qlive = (quad >> 1) == parity;
#pragma unroll
      for (int it = 0; it < 16; ++it) {
        const int tok = it * 16 + n16;
        // key(tok) = bk16 ^ ((2*it)&7): compile-time XOR imm per unrolled it
        h8 Ah = afrag8k(sm, HOFF, tok, quad, bk16 ^ ((2 * it) & 7));
        f4 Cq = MFMA32(BfQ, Ah, bq);   // col n16 = token, row quad*4+r = feat
        f4 Ck = MFMA32(BfK, Ah, bk);
        f4 Cv = MFMA32(Ah, BfV, bv4);  // col n16 = feat, C[r] = token quad*4+r
        uint2 q{pk2(Cq[0], Cq[1]), pk2(Cq[2], Cq[3])};
        if (!qlive) { q.x = 0u; q.y = 0u; }  // zero other head's k-half
        Qf[it] = __builtin_bit_cast(h4, q);
        uint2 kk{pk2(Ck[0], Ck[1]), pk2(Ck[2], Ck[3])};
        Kf[it] = __builtin_bit_cast(h4, kk);
        uint2 v{pk2(Cv[0], Cv[1]), pk2(Cv[2], Cv[3])};
        if (n16 >= 8) { v.x = fill; v.y = fill; }  // row 8 ones, 9-15 zero
        Vf[it] = __builtin_bit_cast(h4, v);
      }
    }
    // No fence: ph1->ph2 is pure register dataflow.

    // ---- ph2: flash attention (wave = head), QKV fully in registers ------
    // r11 pipeline shape (proven spill-free): V8 pairs prebuilt; QK^T
    // software-pipelined WITHIN each it. O-store key decomposed (r14):
    // offset = ob8 ^ compile-time imm — no per-it address temps.
    {
      const int hh  = wave;
      const int m   = n16;
      const int ob8 = ((hh * 2 + quad) ^ bk16) * 8;  // O chunk base (quad<2)
      unsigned char* op = sm + VOFF + m * 64;
      const f4 Z = {0.f, 0.f, 0.f, 0.f};
      h8 V8a[8];
#pragma unroll
      for (int j2 = 0; j2 < 8; ++j2) V8a[j2] = hcat(Vf[2 * j2], Vf[2 * j2 + 1]);
      __builtin_amdgcn_s_setprio(1);
#pragma unroll
      for (int it = 0; it < 16; ++it) {
        h4 Q4 = Qf[it];
        f4 Of0 = Z, Of1 = Z;
        f4 T0 = MFMA16(Kf[0], Q4, Z);
        f4 T1 = MFMA16(Kf[1], Q4, Z);
#pragma unroll
        for (int j2 = 0; j2 < 8; ++j2) {
          f4 nT0 = T0, nT1 = T1;
          if (j2 < 7) {  // prefetch next tile-pair's scores
            nT0 = MFMA16(Kf[2 * j2 + 2], Q4, Z);
            nT1 = MFMA16(Kf[2 * j2 + 3], Q4, Z);
          }
          uint2 pa{pk2(exp2fast(T0[0]), exp2fast(T0[1])),
                   pk2(exp2fast(T0[2]), exp2fast(T0[3]))};
          uint2 pb{pk2(exp2fast(T1[0]), exp2fast(T1[1])),
                   pk2(exp2fast(T1[2]), exp2fast(T1[3]))};
          h8 P8 = hcat(__builtin_bit_cast(h4, pa), __builtin_bit_cast(h4, pb));
          if (j2 & 1) Of1 = MFMA32(V8a[j2], P8, Of1);
          else        Of0 = MFMA32(V8a[j2], P8, Of0);
          T0 = nT0; T1 = nT1;
        }
        f4 Of = Of0 + Of1;
        // C row 8 (quad==2, elem 0) = softmax denominator (lsum trick)
        float rinv = __builtin_amdgcn_rcpf(Of[0]);
        rinv = __builtin_bit_cast(
            float, __builtin_amdgcn_ds_bpermute(
                       (32 + m) << 2, __builtin_bit_cast(int, rinv)));
        if (quad < 2) {  // rows 0..7 = O features hh*8+quad*4+r of token ti
          f4 o = Of * rinv;
          uint2 p{pk2(o[0], o[1]), pk2(o[2], o[3])};
          *(uint2*)(op + it * 1024 + (ob8 ^ (((2 * it) & 7) << 3))) = p;
        }
      }
      __builtin_amdgcn_s_setprio(0);
    }
    // Barrier B: O (cross-head chunks, VOFF) visible to all; also all ph1
    // h-reads finished -> HOFF rows reusable below.
    __syncthreads();

    // ---- GEMM2: O'^T = Wo x O^T; read VOFF, write VOFF own rows ----------
    // key((wave*4+ii)*16+n16) = bk16 ^ ((2*ii)&7): 8*wave drops mod 8.
    {
      const float* Wo = opw + l * D * D;
      const float* Bo = opb + l * D;
      h8 WoF[2]; f4 bo2[2];
#pragma unroll
      for (int nt = 0; nt < 2; ++nt) {
        bo2[nt] = *(const f4*)(Bo + nt * 16 + quad * 4);
        WoF[nt] = bfrag8(Wo, nt * 16 + n16, quad);
      }
#pragma unroll
      for (int ii = 0; ii < 4; ++ii) {
        const int tok = (wave * 4 + ii) * 16 + n16;
        const int key = bk16 ^ ((2 * ii) & 7);
        h8 A8 = afrag8k(sm, VOFF, tok, quad, key);
#pragma unroll
        for (int nt = 0; nt < 2; ++nt) {
          f4 C = MFMA32(WoF[nt], A8, bo2[nt]);
          uint2 p{pk2(C[0], C[1]), pk2(C[2], C[3])};
          *(uint2*)(sm + VOFF + tok * 64 + (((nt * 4 + quad) ^ key) * 8)) = p;
        }
      }
    }
    wave_fence();  // O' rows are own-wave

    // ---- token: h += O'; LN1; h' f16 -> HOFF (own rows; h dead) ----------
    add_row32(sm, VOFF, tid, hk, h);
    lnorm(h, ln1g + l * D, ln1b + l * D);
    store_h16(sm, tid, hk, h);
    wave_fence();

    // ---- fused GEMM3+GEMM4 (t in registers, r5-verified); h' from HOFF ---
    {
      const float* Wa = w1 + l * DFF * D;
      const float* Ba = b1 + l * DFF;
      const float* Wb = w2 + l * D * DFF;
      const float* Bb = b2 + l * D;
      h8 WaF[4]; f4 ba4[4]; h8 WbF[4]; f4 bb2[2];
#pragma unroll
      for (int ft = 0; ft < 4; ++ft) {
        ba4[ft] = *(const f4*)(Ba + ft * 16 + quad * 4);
        WaF[ft] = bfrag8(Wa, ft * 16 + n16, quad);
      }
#pragma unroll
      for (int nt = 0; nt < 2; ++nt) {
        bb2[nt] = *(const f4*)(Bb + nt * 16 + quad * 4);
#pragma unroll
        for (int g = 0; g < 2; ++g)
          WbF[nt * 2 + g] = hcat(bfrag(Wb, nt * 16 + n16, 64, 2 * g, quad),
                                 bfrag(Wb, nt * 16 + n16, 64, 2 * g + 1, quad));
      }
#pragma unroll
      for (int tt = 0; tt < 4; ++tt) {
        const int tok = (wave * 4 + tt) * 16 + n16;
        const int key = bk16 ^ ((2 * tt) & 7);
        h8 A8 = afrag8k(sm, HOFF, tok, quad, key);
        h4 Pf[4];
#pragma unroll
        for (int ft = 0; ft < 4; ++ft) {
          f4 C = MFMA32(WaF[ft], A8, ba4[ft]);
          uint2 p{pk2(gelu(C[0]), gelu(C[1])), pk2(gelu(C[2]), gelu(C[3]))};
          Pf[ft] = __builtin_bit_cast(h4, p);
        }
        h8 P8a = hcat(Pf[0], Pf[1]);
        h8 P8b = hcat(Pf[2], Pf[3]);
#pragma unroll
        for (int nt = 0; nt < 2; ++nt) {
          f4 C = MFMA32(WbF[nt * 2], P8a, bb2[nt]);
          C = MFMA32(WbF[nt * 2 + 1], P8b, C);
          uint2 p{pk2(C[0], C[1]), pk2(C[2], C[3])};
          *(uint2*)(sm + VOFF + tok * 64 + (((nt * 4 + quad) ^ key) * 8)) = p;
        }
      }
    }
    wave_fence();  // O'' rows are own-wave

    // ---- token: h += O''; LN2; h f16 -> HOFF (next layer's ph1 src) ------
    add_row32(sm, VOFF, tid, hk, h);
    lnorm(h, ln2g + l * D, ln2b + l * D);
    if (l < NL - 1) store_h16(sm, tid, hk, h);  // dead after last layer
  }

  // ---------- final LN + head ----------
  __syncthreads();  // staging overlays HOFF+VOFF still read by other waves
  lnorm(h, nog, nob);
  float* hs = (float*)sm;  // 25.6 KB staging over dead HOFF+VOFF
#pragma unroll
  for (int o = 0; o < HOUT; ++o)
    hs[tid * HOUT + o] = dotp<16>(hw + o * D, h) + hb[o];
  __syncthreads();
  f2* og = (f2*)(out + blk_tok * HOUT);
  const f2* os2 = (const f2*)hs;
  for (int i = tid; i < S * HOUT / 2; i += TPB) og[i] = os2[i];
}

extern "C" void kernel_launch(void* const* d_in, const int* in_sizes, int n_in,
                              void* d_out, int out_size, void* d_ws, size_t ws_size,
                              hipStream_t stream) {
  const float* x    = (const float*)d_in[0];
  const int*   lays = (const int*)  d_in[1];
  const float* fpw  = (const float*)d_in[2];
  const float* fpb  = (const float*)d_in[3];
  const float* lemb = (const float*)d_in[4];
  const float* fB   = (const float*)d_in[5];
  const float* ipw  = (const float*)d_in[6];
  const float* ipb  = (const float*)d_in[7];
  const float* opw  = (const float*)d_in[8];
  const float* opb  = (const float*)d_in[9];
  const float* ln1g = (const float*)d_in[10];
  const float* ln1b = (const float*)d_in[11];
  const float* w1   = (const float*)d_in[12];
  const float* b1   = (const float*)d_in[13];
  const float* w2   = (const float*)d_in[14];
  const float* b2   = (const float*)d_in[15];
  const float* ln2g = (const float*)d_in[16];
  const float* ln2b = (const float*)d_in[17];
  const float* nog  = (const float*)d_in[18];
  const float* nob  = (const float*)d_in[19];
  const float* hw   = (const float*)d_in[20];
  const float* hb   = (const float*)d_in[21];
  float* out = (float*)d_out;

  const int nwin = in_sizes[0] / (S * IND);  // 512 windows
  spai_fused<<<nwin, TPB, 0, stream>>>(x, lays, fpw, fpb, lemb, fB, ipw, ipb,
                                       opw, opb, ln1g, ln1b, w1, b1, w2, b2,
                                       ln2g, ln2b, nog, nob, hw, hb, out);
}